// Round 5
// baseline (216.587 us; speedup 1.0000x reference)
//
#include <hip/hip_runtime.h>
#include <math.h>

#define B_ 4
#define S_ 2048
#define G_ 8
#define D_ 128
#define N_ 64
#define ROWS (B_*S_*G_)      // 65536
#define CH 64
#define CLEN 32
#define YOFF (ROWS*D_)       // 8388608

typedef short bf16x8 __attribute__((ext_vector_type(8)));
typedef float f32x4  __attribute__((ext_vector_type(4)));
#define MFMA16(a,b,c) __builtin_amdgcn_mfma_f32_16x16x32_bf16(a,b,c,0,0,0)

__device__ __forceinline__ unsigned short bf16_rtne(float f) {
    unsigned u = __float_as_uint(f);
    unsigned r = (u + 0x7FFFu + ((u >> 16) & 1u)) >> 16;
    return (unsigned short)r;
}
__device__ __forceinline__ void split_bf16(float f, unsigned short &hi, unsigned short &lo) {
    hi = bf16_rtne(f);
    float hif = __uint_as_float(((unsigned)hi) << 16);
    lo = bf16_rtne(f - hif);
}
__device__ __forceinline__ void split4(float4 v, uint2 &hi2, uint2 &lo2) {
    unsigned short h0,h1,h2,h3,l0,l1,l2,l3;
    split_bf16(v.x,h0,l0); split_bf16(v.y,h1,l1);
    split_bf16(v.z,h2,l2); split_bf16(v.w,h3,l3);
    hi2 = make_uint2((unsigned)h0 | ((unsigned)h1<<16), (unsigned)h2 | ((unsigned)h3<<16));
    lo2 = make_uint2((unsigned)l0 | ((unsigned)l1<<16), (unsigned)l2 | ((unsigned)l3<<16));
}
__device__ __forceinline__ float dot4(float4 a, float4 b) {
    return fmaf(a.x,b.x, fmaf(a.y,b.y, fmaf(a.z,b.z, a.w*b.w)));
}

// ============ k_prep: pre-convert weights (hi-bf16) into MFMA frag order ====
// wbhi: [w4][nt2][ks8][lane64] bf16x8 ; wchi: [w4][nt4][ks4][lane64] bf16x8
__global__ __launch_bounds__(256) void k_prep(
    const float* __restrict__ bwr, const float* __restrict__ bwi,
    const float* __restrict__ cwr, const float* __restrict__ cwi,
    unsigned short* __restrict__ wbhi, unsigned short* __restrict__ wchi)
{
    int tid = blockIdx.x * 256 + threadIdx.x;   // [0, 8192)
    if (tid < 4096) {
        int f = tid;
        int lane = f & 63, ks = (f >> 6) & 7, nt = (f >> 9) & 1, w = f >> 10;
        int l15 = lane & 15, quad = lane >> 4;
        int n = w * 32 + nt * 16 + l15;
        int k0 = ks * 32 + quad * 8;
        const float* src; float sgn = 1.f;
        if (n < 64) {
            if (k0 < 128) src = bwr + n * 128 + k0;
            else        { src = bwi + n * 128 + (k0 - 128); sgn = -1.f; }
        } else {
            if (k0 < 128) src = bwi + (n - 64) * 128 + k0;
            else          src = bwr + (n - 64) * 128 + (k0 - 128);
        }
        float4 v0 = *(const float4*)src;
        float4 v1 = *(const float4*)(src + 4);
        float vv[8] = {v0.x,v0.y,v0.z,v0.w,v1.x,v1.y,v1.z,v1.w};
        #pragma unroll
        for (int j = 0; j < 8; j++) wbhi[f*8+j] = bf16_rtne(vv[j] * sgn);
    } else {
        int f = tid - 4096;
        int lane = f & 63, ks = (f >> 6) & 3, nt = (f >> 8) & 3, w = f >> 10;
        int l15 = lane & 15, quad = lane >> 4;
        int n = w * 64 + nt * 16 + l15;
        int d = (n < 128) ? n : (n - 128);
        int k0 = ks * 32 + quad * 8;
        const float* src; float sgn = 1.f;
        if (n < 128) {
            if (k0 < 64) src = cwr + d * 64 + k0;
            else       { src = cwi + d * 64 + (k0 - 64); sgn = -1.f; }
        } else {
            if (k0 < 64) src = cwi + d * 64 + k0;
            else         src = cwr + d * 64 + (k0 - 64);
        }
        float4 v0 = *(const float4*)src;
        float4 v1 = *(const float4*)(src + 4);
        float vv[8] = {v0.x,v0.y,v0.z,v0.w,v1.x,v1.y,v1.z,v1.w};
        #pragma unroll
        for (int j = 0; j < 8; j++) wchi[f*8+j] = bf16_rtne(vv[j] * sgn);
    }
}

// ============ G1: dt + Bx GEMM + chunk-transition compose ===================
// block = (bg, cq in [0,32)): 2 chunks. 2-MFMA x-split: (A_hi+A_lo) x W_hi.
// Bx packed bf16 (r|i<<16) to HBM via LDS pack phase.
#define LDK1 280
__global__ __launch_bounds__(256, 4) void k_g1(
    const float* __restrict__ xr, const float* __restrict__ xi,
    const float* __restrict__ dtw, const float* __restrict__ dtb,
    const float* __restrict__ logAm, const float* __restrict__ Aph,
    const unsigned short* __restrict__ wbhi,
    unsigned int* __restrict__ bxp,
    float* __restrict__ dt_mag, float* __restrict__ dt_ph,
    float4* __restrict__ trans)
{
    __shared__ __align__(16) unsigned short Ahi[32 * LDK1];
    __shared__ __align__(16) unsigned short Alo[32 * LDK1];
    __shared__ float dms[32], dps[32];
    __shared__ float4 comb[64];
    float* bxs = (float*)Ahi;   // overlay after MFMA reads (16.9KB <= 17.9KB)
    const int t = threadIdx.x;
    const int lane = t & 63, w = t >> 6;
    const int l15 = lane & 15, quad = lane >> 4;
    const int bg = blockIdx.x >> 5, cq = blockIdx.x & 31;
    const int g = bg & 7, b = bg >> 3;

    bf16x8 wh[2][8];
    #pragma unroll
    for (int nt = 0; nt < 2; nt++)
        #pragma unroll
        for (int ks = 0; ks < 8; ks++)
            wh[nt][ks] = ((const bf16x8*)wbhi)[((w * 2 + nt) * 8 + ks) * 64 + lane];

    const int kq = t & 31, k4 = kq * 4;
    float4 w0r = *(const float4*)(dtw + k4);
    float4 w0i = *(const float4*)(dtw + 128 + k4);
    float4 w1r = *(const float4*)(dtw + 256 + k4);
    float4 w1i = *(const float4*)(dtw + 384 + k4);
    float b0 = dtb[0], b1 = dtb[1];
    float nla = -logf(1.0f + __expf(logAm[g * N_ + lane]));
    float aph = Aph[g * N_ + lane];

    for (int it = 0; it < 2; it++) {
        __syncthreads();   // protect bxs/comb from new staging writes
        const int c  = cq * 2 + it;
        const int s0 = c * CLEN;
        const float* xrb = xr + ((size_t)(b * S_ + s0) * G_ + g) * 128;
        const float* xib = xi + ((size_t)(b * S_ + s0) * G_ + g) * 128;
        float pm[4], pp[4];
        #pragma unroll
        for (int i = 0; i < 4; i++) {
            int f = t + 256 * i;
            int m = f >> 5, kk = f & 31;
            float4 a  = ((const float4*)(xrb + m * 1024))[kk];
            float4 bb = ((const float4*)(xib + m * 1024))[kk];
            uint2 h2, l2;
            split4(a, h2, l2);
            *(uint2*)&Ahi[m * LDK1 + kk * 4] = h2;
            *(uint2*)&Alo[m * LDK1 + kk * 4] = l2;
            split4(bb, h2, l2);
            *(uint2*)&Ahi[m * LDK1 + 128 + kk * 4] = h2;
            *(uint2*)&Alo[m * LDK1 + 128 + kk * 4] = l2;
            pm[i] = dot4(a, w0r) + dot4(bb, w0i);
            pp[i] = dot4(a, w1r) + dot4(bb, w1i);
        }
        #pragma unroll
        for (int i = 0; i < 4; i++) {
            float vm = pm[i], vp = pp[i];
            #pragma unroll
            for (int msk = 16; msk >= 1; msk >>= 1) {
                vm += __shfl_xor(vm, msk);
                vp += __shfl_xor(vp, msk);
            }
            if ((t & 31) == 0) {
                int m = (t >> 5) + 8 * i;
                float dm = fminf(fmaxf(__expf(vm + b0), 1e-4f), 2.0f);
                float dp = fminf(fmaxf(__expf(vp + b1), 1e-4f), 2.0f);
                dms[m] = dm; dps[m] = dp;
                int row = (b * S_ + s0 + m) * G_ + g;
                dt_mag[row] = dm; dt_ph[row] = dp;
            }
        }
        __syncthreads();

        f32x4 acc[2][2];
        #pragma unroll
        for (int a = 0; a < 2; a++)
            #pragma unroll
            for (int bq = 0; bq < 2; bq++)
                acc[a][bq] = (f32x4){0.f, 0.f, 0.f, 0.f};
        #pragma unroll
        for (int ms = 0; ms < 2; ms++) {
            int arow = (ms * 16 + l15) * LDK1 + quad * 8;
            #pragma unroll
            for (int ks = 0; ks < 8; ks++) {
                bf16x8 ah = *(const bf16x8*)&Ahi[arow + ks * 32];
                bf16x8 al = *(const bf16x8*)&Alo[arow + ks * 32];
                #pragma unroll
                for (int nt = 0; nt < 2; nt++) {
                    acc[ms][nt] = MFMA16(al, wh[nt][ks], acc[ms][nt]);
                    acc[ms][nt] = MFMA16(ah, wh[nt][ks], acc[ms][nt]);
                }
            }
        }
        __syncthreads();   // staging reads done; Ahi region becomes bxs

        // park Bx (scaled) in LDS
        #pragma unroll
        for (int ms = 0; ms < 2; ms++)
            #pragma unroll
            for (int nt = 0; nt < 2; nt++) {
                int n = w * 32 + nt * 16 + l15;
                #pragma unroll
                for (int r = 0; r < 4; r++) {
                    int m = ms * 16 + quad * 4 + r;
                    bxs[m * 132 + n] = acc[ms][nt][r] * dms[m];
                }
            }
        __syncthreads();

        // pack to global bf16x2 (all waves, coalesced 256B per wave-row)
        #pragma unroll
        for (int j = 0; j < 8; j++) {
            int idx = j * 256 + t;
            int m = idx >> 6, n = idx & 63;
            float vr = bxs[m * 132 + n], vi = bxs[m * 132 + 64 + n];
            unsigned pr = bf16_rtne(vr), pi = bf16_rtne(vi);
            bxp[((b * S_ + s0 + m) * G_ + g) * 64 + n] = pr | (pi << 16);
        }

        // compose chunk transition: wave 0 = steps 0..15, wave 1 = 16..31
        float Ar = 1.f, Ai = 0.f, Br = 0.f, Bi = 0.f;
        if (w < 2) {
            int base = w * 16;
            #pragma unroll
            for (int tt = 0; tt < 16; tt++) {
                int m = base + tt;
                float dm = dms[m], dp = dps[m];
                float am  = __expf(dm * nla);
                float ang = dp * aph;
                float cr = am * __cosf(ang), ci = am * __sinf(ang);
                float vr = bxs[m * 132 + lane], vi = bxs[m * 132 + 64 + lane];
                float nAr = cr * Ar - ci * Ai;
                float nAi = cr * Ai + ci * Ar;
                float nBr = cr * Br - ci * Bi + vr;
                float nBi = cr * Bi + ci * Br + vi;
                Ar = nAr; Ai = nAi; Br = nBr; Bi = nBi;
            }
            if (w == 0) comb[lane] = make_float4(Ar, Ai, Br, Bi);
        }
        __syncthreads();
        if (w == 1) {
            float4 c0 = comb[lane];
            float fAr = Ar * c0.x - Ai * c0.y;
            float fAi = Ar * c0.y + Ai * c0.x;
            float fBr = Ar * c0.z - Ai * c0.w + Br;
            float fBi = Ar * c0.w + Ai * c0.z + Bi;
            trans[(bg * CH + c) * 64 + lane] = make_float4(fAr, fAi, fBr, fBi);
        }
    }
}

// ============ SG2: chunk-prefix combine + scanC + y GEMM (all fused) ========
// block = (bg, cq in [0,16)): wave w owns chunk c = cq*4+w. Wave composes its
// own prefix from trans (renorm every 8 chunks), scans its chunk from bf16 bx,
// stages h (hi-bf16) in LDS, then M=128 GEMM in 8 ms-tiles (1-MFMA, acc=16).
#define LDK2 136
__global__ __launch_bounds__(256, 4) void k_sg2(
    const unsigned int* __restrict__ bxp,
    const float* __restrict__ dt_mag, const float* __restrict__ dt_ph,
    const float* __restrict__ logAm, const float* __restrict__ Aph,
    const float4* __restrict__ trans,
    const unsigned short* __restrict__ wchi,
    float* __restrict__ out)
{
    __shared__ __align__(16) unsigned short Ahi[128 * LDK2];
    const int t = threadIdx.x;
    const int lane = t & 63, w = t >> 6;
    const int l15 = lane & 15, quad = lane >> 4;
    const int bg = blockIdx.x >> 4, cq = blockIdx.x & 15;
    const int g = bg & 7, b = bg >> 3;

    bf16x8 wc[4][4];
    #pragma unroll
    for (int nt = 0; nt < 4; nt++)
        #pragma unroll
        for (int ks = 0; ks < 4; ks++)
            wc[nt][ks] = ((const bf16x8*)wchi)[((w * 4 + nt) * 4 + ks) * 64 + lane];

    {
        const int n = lane;
        const int c = cq * 4 + w;
        // ---- inline chunk-prefix combine (replaces scanB2/hstart) ----
        float hr = 0.f, hi = 0.f;
        const float4* tp = trans + (bg * CH) * 64 + n;
        for (int k = 0; k < c; k++) {
            float4 T = tp[k * 64];
            float nr = T.x * hr - T.y * hi + T.z;
            float ni = T.x * hi + T.y * hr + T.w;
            if ((k & 7) == 7) {
                float nrm = sqrtf(nr * nr + ni * ni + 1e-8f);
                float sc = fminf(nrm, 100.f) / nrm;
                nr *= sc; ni *= sc;
            }
            hr = nr; hi = ni;
        }
        // ---- in-chunk scan ----
        float nla = -logf(1.0f + __expf(logAm[g * N_ + n]));
        float aph = Aph[g * N_ + n];
        const bool rn = ((c & 7) == 7);
        const int rowbase = (b * S_ + c * CLEN) * G_ + g;
        #pragma unroll 8
        for (int tt = 0; tt < CLEN; tt++) {
            int row = rowbase + tt * G_;
            float dm = dt_mag[row], dp = dt_ph[row];
            float am  = __expf(dm * nla);
            float ang = dp * aph;
            float cr = am * __cosf(ang), ci = am * __sinf(ang);
            unsigned p = bxp[row * 64 + n];
            float vr = __uint_as_float(p << 16);
            float vi = __uint_as_float(p & 0xFFFF0000u);
            float nr = cr * hr - ci * hi + vr;
            float ni = cr * hi + ci * hr + vi;
            if (rn && tt == CLEN - 1) {
                float nrm = sqrtf(nr * nr + ni * ni + 1e-8f);
                float scale = fminf(nrm, 100.0f) / nrm;
                nr *= scale; ni *= scale;
            }
            hr = nr; hi = ni;
            int m = w * 32 + tt;
            Ahi[m * LDK2 + n]      = bf16_rtne(hr);
            Ahi[m * LDK2 + 64 + n] = bf16_rtne(hi);
        }
    }
    __syncthreads();

    // ---- GEMM: 8 ms-tiles of 16 rows, acc[4] each (1-MFMA, hi only) ----
    #pragma unroll
    for (int ms = 0; ms < 8; ms++) {
        f32x4 acc[4];
        #pragma unroll
        for (int nt = 0; nt < 4; nt++) acc[nt] = (f32x4){0.f, 0.f, 0.f, 0.f};
        int arow = (ms * 16 + l15) * LDK2 + quad * 8;
        #pragma unroll
        for (int ks = 0; ks < 4; ks++) {
            bf16x8 ah = *(const bf16x8*)&Ahi[arow + ks * 32];
            #pragma unroll
            for (int nt = 0; nt < 4; nt++)
                acc[nt] = MFMA16(ah, wc[nt][ks], acc[nt]);
        }
        #pragma unroll
        for (int nt = 0; nt < 4; nt++) {
            int nn = w * 64 + nt * 16 + l15;
            float* dst = (nn < 128) ? (out + nn) : (out + YOFF + (nn - 128));
            #pragma unroll
            for (int r = 0; r < 4; r++) {
                int m_local = ms * 16 + quad * 4 + r;
                int cc = m_local >> 5, tt2 = m_local & 31;
                int srow = (b * S_ + (cq * 4 + cc) * CLEN + tt2) * G_ + g;
                dst[srow * 128] = acc[nt][r];
            }
        }
    }
}

extern "C" void kernel_launch(void* const* d_in, const int* in_sizes, int n_in,
                              void* d_out, int out_size, void* d_ws, size_t ws_size,
                              hipStream_t stream) {
    (void)in_sizes; (void)n_in; (void)out_size; (void)ws_size;
    const float* xr    = (const float*)d_in[0];
    const float* xi    = (const float*)d_in[1];
    const float* logAm = (const float*)d_in[2];
    const float* Aph   = (const float*)d_in[3];
    const float* bwr   = (const float*)d_in[4];
    const float* bwi   = (const float*)d_in[5];
    const float* cwr   = (const float*)d_in[6];
    const float* cwi   = (const float*)d_in[7];
    const float* dtw   = (const float*)d_in[8];
    const float* dtb   = (const float*)d_in[9];
    float* out = (float*)d_out;
    float* ws  = (float*)d_ws;

    float*        dt_mag = ws;                              // 65536
    float*        dt_ph  = ws + 65536;                      // 65536
    unsigned int* bxp    = (unsigned int*)(ws + 131072);    // 4194304 uints
    float4*       trans  = (float4*)(ws + 4325376);         // 131072 float4
    unsigned short* wbhi = (unsigned short*)(ws + 4849664); // 32768 shorts
    unsigned short* wchi = wbhi + 32768;                    // 32768 shorts

    hipLaunchKernelGGL(k_prep, dim3(32), dim3(256), 0, stream,
                       bwr, bwi, cwr, cwi, wbhi, wchi);
    hipLaunchKernelGGL(k_g1,   dim3((B_ * G_) * 32), dim3(256), 0, stream,
                       xr, xi, dtw, dtb, logAm, Aph, wbhi,
                       bxp, dt_mag, dt_ph, trans);
    hipLaunchKernelGGL(k_sg2,  dim3((B_ * G_) * 16), dim3(256), 0, stream,
                       bxp, dt_mag, dt_ph, logAm, Aph, trans, wchi, out);
}